// Round 10
// baseline (735.939 us; speedup 1.0000x reference)
//
#include <hip/hip_runtime.h>
#include <hip/hip_bf16.h>

// ---------------------------------------------------------------------------
// Bidirectional LSTM encoder: B=128, T=512, V=32000, E=256, H=128
//   k0: prep_emb — emb fp32 -> bf16 (ws)
//   k1: prep_wt  — W fp32 -> Wt bf16 [n=1024][k=256] (ws)
//   k2: gemm_xw  — xw[dir][b*T+t][4H] bf16 = emb_bf16[tok] @ W   (MFMA)
//   k3: prep_ut  — U fp32 -> Ut [k4][dir*512+col][4] (coalesced b128 per col)
//   k4: lstm_rec — 256 blocks = (dir,b), 1024 threads.
// Round-9 diagnosis: rounds 3-8 all kept U in a 512-byte per-thread ARRAY
// (float[128] / f32x4[32]) -> promote-alloca fails on AMDGPU -> the column
// lived in SCRATCH, streamed 512B/thr/step from L2 (~1700 extra cyc/step;
// VGPR_Count 84-96 the tell; invisible in FETCH_SIZE since scratch is
// L2-resident). Fix: 1024 threads, each owns HALF a column as 16 NAMED
// f32x4 vars (no alloca, 64 VGPRs); halves combined via pz[] in LDS.
// 16 waves/CU (4/SIMD) also doubles latency hiding.
// ---------------------------------------------------------------------------

typedef short short8 __attribute__((ext_vector_type(8)));
typedef float f32x4 __attribute__((ext_vector_type(4)));

#define GLL16(g, l)                                                        \
  __builtin_amdgcn_global_load_lds(                                        \
      (const __attribute__((address_space(1))) void*)(g),                  \
      (__attribute__((address_space(3))) void*)(l), 16, 0, 0)

__device__ __forceinline__ unsigned short f2bf(float f) {
  __hip_bfloat16 h = __float2bfloat16(f);
  return __builtin_bit_cast(unsigned short, h);
}

__device__ __forceinline__ float fast_sigmoid(float z) {
  return 1.f / (1.f + __expf(-z));          // z->+inf:1, z->-inf:0, NaN-free
}
__device__ __forceinline__ float fast_tanh(float z) {
  return 1.f - 2.f / (__expf(2.f * z) + 1.f);  // exact +-1 at extremes
}

// ---- k0: convert embedding table to bf16 ----------------------------------
__global__ void prep_emb(const float4* __restrict__ in,
                         ushort4* __restrict__ outp, int n4) {
  int i = blockIdx.x * blockDim.x + threadIdx.x;
  if (i < n4) {
    float4 v = in[i];
    ushort4 o;
    o.x = f2bf(v.x); o.y = f2bf(v.y); o.z = f2bf(v.z); o.w = f2bf(v.w);
    outp[i] = o;
  }
}

// ---- k1: build Wt bf16 [1024 n][256 k] ------------------------------------
__global__ void prep_wt(const float* __restrict__ Wfw,
                        const float* __restrict__ Wbw,
                        __hip_bfloat16* __restrict__ Wt) {
  int n = blockIdx.x;
  int k = threadIdx.x;
  const float* W = (n < 512) ? Wfw : Wbw;
  Wt[n * 256 + k] = __float2bfloat16(W[k * 512 + (n & 511)]);
}

// ---- k2: gathered MFMA GEMM:  xw = emb_bf16[tokens] @ W -------------------
__global__ __launch_bounds__(256) void gemm_xw(
    const int* __restrict__ tokens, const __hip_bfloat16* __restrict__ embb,
    const __hip_bfloat16* __restrict__ Wt, __hip_bfloat16* __restrict__ xw) {
  __shared__ __attribute__((aligned(16))) __hip_bfloat16 As[128 * 32];
  __shared__ __attribute__((aligned(16))) __hip_bfloat16 Bs[128 * 32];
  const int tid = threadIdx.x;
  const int bm = blockIdx.x;
  const int bn = blockIdx.y;
  const int lane = tid & 63, w = tid >> 6;

  const int ar = tid >> 2;
  const int kcol = (tid & 3) * 8;
  const long r0 = (long)bm * 128 + ar;
  const int tok0 = tokens[r0];
  const int tok1 = tokens[r0 + 64];
  const __hip_bfloat16* a0 = embb + (size_t)tok0 * 256 + kcol;
  const __hip_bfloat16* a1 = embb + (size_t)tok1 * 256 + kcol;
  const __hip_bfloat16* bs0 = Wt + ((size_t)bn * 128 + ar) * 256 + kcol;
  const __hip_bfloat16* bs1 = bs0 + 64 * 256;
  __hip_bfloat16* As_d0 = As + tid * 8;
  __hip_bfloat16* As_d1 = As + 2048 + tid * 8;
  __hip_bfloat16* Bs_d0 = Bs + tid * 8;
  __hip_bfloat16* Bs_d1 = Bs + 2048 + tid * 8;

  f32x4 acc[4][4];
#pragma unroll
  for (int i = 0; i < 4; ++i)
#pragma unroll
    for (int j = 0; j < 4; ++j) acc[i][j] = (f32x4){0.f, 0.f, 0.f, 0.f};

  const int fm = (w >> 1) * 64, fn = (w & 1) * 64;
  const int lr = lane & 15, lk = (lane >> 4) * 8;

  for (int kk = 0; kk < 8; ++kk) {
    GLL16(a0 + kk * 32, As_d0);
    GLL16(a1 + kk * 32, As_d1);
    GLL16(bs0 + kk * 32, Bs_d0);
    GLL16(bs1 + kk * 32, Bs_d1);
    __syncthreads();
    short8 af[4], bfr[4];
#pragma unroll
    for (int i = 0; i < 4; ++i)
      af[i] = *(const short8*)(As + (fm + 16 * i + lr) * 32 + lk);
#pragma unroll
    for (int j = 0; j < 4; ++j)
      bfr[j] = *(const short8*)(Bs + (fn + 16 * j + lr) * 32 + lk);
#pragma unroll
    for (int i = 0; i < 4; ++i)
#pragma unroll
      for (int j = 0; j < 4; ++j)
        acc[i][j] = __builtin_amdgcn_mfma_f32_16x16x32_bf16(af[i], bfr[j],
                                                            acc[i][j], 0, 0, 0);
    __syncthreads();
  }

  const int orow = (lane >> 4) * 4;
#pragma unroll
  for (int i = 0; i < 4; ++i)
#pragma unroll
    for (int j = 0; j < 4; ++j)
#pragma unroll
      for (int r = 0; r < 4; ++r) {
        int row_local = fm + 16 * i + orow + r;
        int col_local = fn + 16 * j + (lane & 15);
        size_t rg = (size_t)bm * 128 + row_local;
        int ng = bn * 128 + col_local;
        size_t addr = (size_t)(ng >> 9) * 33554432ull + rg * 512 + (ng & 511);
        xw[addr] = __float2bfloat16(acc[i][j][r]);
      }
}

// ---- k3: transpose U -> Ut [k4 (32)][dir*512+col (1024)][4] fp32 ----------
__global__ void prep_ut(const float* __restrict__ Ufw,
                        const float* __restrict__ Ubw,
                        float* __restrict__ Ut) {
  int idx = blockIdx.x * 512 + threadIdx.x;  // 0..131071
  int j = idx & 3;
  int dc = (idx >> 2) & 1023;
  int k4 = idx >> 12;
  int k = 4 * k4 + j;
  int c = dc & 511;
  const float* U = (dc >> 9) ? Ubw : Ufw;
  Ut[idx] = U[k * 512 + c];
}

// ---- k4: recurrence. 1024 thr; thread (col, kh) owns U[64kh..64kh+63][col]
// as 16 NAMED f32x4 (no alloca -> guaranteed VGPR residency).
__global__ __launch_bounds__(1024) void lstm_rec(
    const float* __restrict__ Ut, const float* __restrict__ b_fw,
    const float* __restrict__ b_bw, const __hip_bfloat16* __restrict__ xw,
    float* __restrict__ out) {
  __shared__ __attribute__((aligned(16))) float h_lds[128];
  __shared__ float pz[1024];
  __shared__ float g_lds[512];
  const int tid = threadIdx.x;
  const int col = tid & 511;   // gate column
  const int kh = tid >> 9;     // 0: k in [0,64), 1: k in [64,128)
  const int dir = blockIdx.x >> 7;
  const int b = blockIdx.x & 127;

  // 16 named f32x4 = 64 VGPRs; uj = U[64*kh+4j .. +3][col]
  const float* up = Ut + ((size_t)kh * 16 * 1024 + dir * 512 + col) * 4;
#define ULOAD(j) f32x4 u##j = *(const f32x4*)(up + (j) * 4096);
  ULOAD(0) ULOAD(1) ULOAD(2) ULOAD(3) ULOAD(4) ULOAD(5) ULOAD(6) ULOAD(7)
  ULOAD(8) ULOAD(9) ULOAD(10) ULOAD(11) ULOAD(12) ULOAD(13) ULOAD(14) ULOAD(15)
#undef ULOAD
  asm volatile("" ::"v"(u0), "v"(u1), "v"(u2), "v"(u3), "v"(u4), "v"(u5),
               "v"(u6), "v"(u7), "v"(u8), "v"(u9), "v"(u10), "v"(u11),
               "v"(u12), "v"(u13), "v"(u14), "v"(u15));

  if (tid < 128) h_lds[tid] = 0.f;
  float c = 0.f, h = 0.f, hfin = 0.f;
  __syncthreads();

  const float bias = (dir ? b_bw : b_fw)[col];
  const __hip_bfloat16* xb =
      xw + (size_t)dir * 33554432ull + (size_t)b * 262144ull + col;
  float* outb = out + (size_t)b * 131072 + dir * 128;  // [B,T,2H] row block

  int t = dir ? 511 : 0;
  const int st = dir ? -1 : 1;
  __hip_bfloat16 xc = __float2bfloat16(0.f);
  if (kh) xc = xb[(size_t)t * 512];
  const float4* h4 = (const float4*)h_lds;
  const int grp = col >> 7;  // 0:i 1:f 2:g 3:o (wave-uniform)
  const int hb = kh * 16;

  for (int it = 0; it < 512; ++it) {
    const int tn = (it == 511) ? t : (t + st);
    __hip_bfloat16 xn = xc;
    if (kh) xn = xb[(size_t)tn * 512];  // prefetch next step (kh=1 waves)
    float a0 = 0.f, a1 = 0.f, a2 = 0.f, a3 = 0.f;
#define UFMA(j)                                         \
  {                                                     \
    float4 hv = h4[hb + (j)]; /* LDS broadcast read */  \
    a0 = fmaf(hv.x, u##j.x, a0);                        \
    a1 = fmaf(hv.y, u##j.y, a1);                        \
    a2 = fmaf(hv.z, u##j.z, a2);                        \
    a3 = fmaf(hv.w, u##j.w, a3);                        \
  }
    UFMA(0) UFMA(1) UFMA(2) UFMA(3) UFMA(4) UFMA(5) UFMA(6) UFMA(7)
    UFMA(8) UFMA(9) UFMA(10) UFMA(11) UFMA(12) UFMA(13) UFMA(14) UFMA(15)
#undef UFMA
    float partial = (a0 + a1) + (a2 + a3);
    if (kh) partial += __bfloat162float(xc) + bias;  // fold x+b into kh=1 half
    pz[tid] = partial;
    __syncthreads();  // B1: pz visible
    if (tid < 512) {
      float z = pz[col] + pz[col + 512];
      g_lds[col] = (grp == 2) ? fast_tanh(z) : fast_sigmoid(z);
    }
    __syncthreads();  // B2: gates visible
    if (tid < 128) {
      c = g_lds[128 + tid] * c + g_lds[tid] * g_lds[256 + tid];
      h = g_lds[384 + tid] * fast_tanh(c);
      hfin = h;
      h_lds[tid] = h;
    }
    __syncthreads();  // B3: h visible for next step
    if (tid < 128) outb[(size_t)t * 256 + tid] = h;  // overlaps next dot-prod
    xc = xn;
    t = tn;
  }
  if (tid < 128) {
    float* o2 = out + 16777216;  // after [B,T,2H]
    o2[dir * 32768 + b * 128 + tid] = hfin;           // h_fw / h_bw
    o2[dir * 32768 + 16384 + b * 128 + tid] = c;      // c_fw / c_bw
  }
}

// ---------------------------------------------------------------------------
extern "C" void kernel_launch(void* const* d_in, const int* in_sizes, int n_in,
                              void* d_out, int out_size, void* d_ws,
                              size_t ws_size, hipStream_t stream) {
  const int* tokens = (const int*)d_in[0];
  const float* emb = (const float*)d_in[1];
  const float* W_fw = (const float*)d_in[2];
  const float* U_fw = (const float*)d_in[3];
  const float* b_fw = (const float*)d_in[4];
  const float* W_bw = (const float*)d_in[5];
  const float* U_bw = (const float*)d_in[6];
  const float* b_bw = (const float*)d_in[7];
  float* out = (float*)d_out;

  char* ws = (char*)d_ws;
  __hip_bfloat16* embb = (__hip_bfloat16*)(ws);               // 16,384,000 B
  __hip_bfloat16* Wt = (__hip_bfloat16*)(ws + 16384000);      //    524,288 B
  __hip_bfloat16* xw = (__hip_bfloat16*)(ws + 16908288);      // 134,217,728 B
  float* Ut = (float*)(ws);  // 524,288 B — overlaps embb (dead after gemm_xw)

  prep_emb<<<8000, 256, 0, stream>>>((const float4*)emb, (ushort4*)embb,
                                     2048000);
  prep_wt<<<1024, 256, 0, stream>>>(W_fw, W_bw, Wt);
  gemm_xw<<<dim3(512, 8), 256, 0, stream>>>(tokens, embb, Wt, xw);
  prep_ut<<<256, 512, 0, stream>>>(U_fw, U_bw, Ut);  // after gemm: reuses embb
  lstm_rec<<<256, 1024, 0, stream>>>(Ut, b_fw, b_bw, xw, out);
}

// Round 14
// 647.219 us; speedup vs baseline: 1.1371x; 1.1371x over previous
//
#include <hip/hip_runtime.h>
#include <hip/hip_bf16.h>

// ---------------------------------------------------------------------------
// Bidirectional LSTM encoder: B=128, T=512, V=32000, E=256, H=128
//   k0: prep_emb — emb fp32 -> bf16 (ws)
//   k1: prep_wt  — W fp32 -> Wt bf16 [n=1024][k=256] (ws)
//   k2: gemm_xw  — xw[dir][b*T+t][4H] bf16 = emb_bf16[tok] @ W   (MFMA)
//   k3: prep_ut  — U fp32 -> Ut [k4][dir*512+col][4] (coalesced b128 per col)
//   k4: lstm_rec — 256 blocks = (dir,b), 512 threads; U column in VGPRs.
// Round-11 synthesis of the two half-fixes:
//   r7: asm-volatile loads (non-remat) but into an ARRAY -> alloca/scratch.
//   r10: NAMED vars (no alloca) but plain loads -> remat'd into the loop
//        (VGPR_Count=64 proved it; 16 f32x4 alone would need 64).
//   Now: asm volatile global_load_dwordx4 into 32 NAMED f32x4. Asm outputs
//   cannot be rematerialized and have no alloca -> must stay in VGPRs.
//   512 threads / 2 barriers (best baseline, 517us); waves_per_eu(2,2) for
//   the 256-VGPR budget. Scratch-spill failure mode would show as a
//   FETCH_SIZE explosion (scratch re-reads) — validation bit.
// ---------------------------------------------------------------------------

typedef short short8 __attribute__((ext_vector_type(8)));
typedef float f32x4 __attribute__((ext_vector_type(4)));

#define GLL16(g, l)                                                        \
  __builtin_amdgcn_global_load_lds(                                        \
      (const __attribute__((address_space(1))) void*)(g),                  \
      (__attribute__((address_space(3))) void*)(l), 16, 0, 0)

__device__ __forceinline__ unsigned short f2bf(float f) {
  __hip_bfloat16 h = __float2bfloat16(f);
  return __builtin_bit_cast(unsigned short, h);
}

__device__ __forceinline__ float fast_sigmoid(float z) {
  return 1.f / (1.f + __expf(-z));          // z->+inf:1, z->-inf:0, NaN-free
}
__device__ __forceinline__ float fast_tanh(float z) {
  return 1.f - 2.f / (__expf(2.f * z) + 1.f);  // exact +-1 at extremes
}

// ---- k0: convert embedding table to bf16 ----------------------------------
__global__ void prep_emb(const float4* __restrict__ in,
                         ushort4* __restrict__ outp, int n4) {
  int i = blockIdx.x * blockDim.x + threadIdx.x;
  if (i < n4) {
    float4 v = in[i];
    ushort4 o;
    o.x = f2bf(v.x); o.y = f2bf(v.y); o.z = f2bf(v.z); o.w = f2bf(v.w);
    outp[i] = o;
  }
}

// ---- k1: build Wt bf16 [1024 n][256 k] ------------------------------------
__global__ void prep_wt(const float* __restrict__ Wfw,
                        const float* __restrict__ Wbw,
                        __hip_bfloat16* __restrict__ Wt) {
  int n = blockIdx.x;
  int k = threadIdx.x;
  const float* W = (n < 512) ? Wfw : Wbw;
  Wt[n * 256 + k] = __float2bfloat16(W[k * 512 + (n & 511)]);
}

// ---- k2: gathered MFMA GEMM:  xw = emb_bf16[tokens] @ W -------------------
__global__ __launch_bounds__(256) void gemm_xw(
    const int* __restrict__ tokens, const __hip_bfloat16* __restrict__ embb,
    const __hip_bfloat16* __restrict__ Wt, __hip_bfloat16* __restrict__ xw) {
  __shared__ __attribute__((aligned(16))) __hip_bfloat16 As[128 * 32];
  __shared__ __attribute__((aligned(16))) __hip_bfloat16 Bs[128 * 32];
  const int tid = threadIdx.x;
  const int bm = blockIdx.x;
  const int bn = blockIdx.y;
  const int lane = tid & 63, w = tid >> 6;

  const int ar = tid >> 2;
  const int kcol = (tid & 3) * 8;
  const long r0 = (long)bm * 128 + ar;
  const int tok0 = tokens[r0];
  const int tok1 = tokens[r0 + 64];
  const __hip_bfloat16* a0 = embb + (size_t)tok0 * 256 + kcol;
  const __hip_bfloat16* a1 = embb + (size_t)tok1 * 256 + kcol;
  const __hip_bfloat16* bs0 = Wt + ((size_t)bn * 128 + ar) * 256 + kcol;
  const __hip_bfloat16* bs1 = bs0 + 64 * 256;
  __hip_bfloat16* As_d0 = As + tid * 8;
  __hip_bfloat16* As_d1 = As + 2048 + tid * 8;
  __hip_bfloat16* Bs_d0 = Bs + tid * 8;
  __hip_bfloat16* Bs_d1 = Bs + 2048 + tid * 8;

  f32x4 acc[4][4];
#pragma unroll
  for (int i = 0; i < 4; ++i)
#pragma unroll
    for (int j = 0; j < 4; ++j) acc[i][j] = (f32x4){0.f, 0.f, 0.f, 0.f};

  const int fm = (w >> 1) * 64, fn = (w & 1) * 64;
  const int lr = lane & 15, lk = (lane >> 4) * 8;

  for (int kk = 0; kk < 8; ++kk) {
    GLL16(a0 + kk * 32, As_d0);
    GLL16(a1 + kk * 32, As_d1);
    GLL16(bs0 + kk * 32, Bs_d0);
    GLL16(bs1 + kk * 32, Bs_d1);
    __syncthreads();
    short8 af[4], bfr[4];
#pragma unroll
    for (int i = 0; i < 4; ++i)
      af[i] = *(const short8*)(As + (fm + 16 * i + lr) * 32 + lk);
#pragma unroll
    for (int j = 0; j < 4; ++j)
      bfr[j] = *(const short8*)(Bs + (fn + 16 * j + lr) * 32 + lk);
#pragma unroll
    for (int i = 0; i < 4; ++i)
#pragma unroll
      for (int j = 0; j < 4; ++j)
        acc[i][j] = __builtin_amdgcn_mfma_f32_16x16x32_bf16(af[i], bfr[j],
                                                            acc[i][j], 0, 0, 0);
    __syncthreads();
  }

  const int orow = (lane >> 4) * 4;
#pragma unroll
  for (int i = 0; i < 4; ++i)
#pragma unroll
    for (int j = 0; j < 4; ++j)
#pragma unroll
      for (int r = 0; r < 4; ++r) {
        int row_local = fm + 16 * i + orow + r;
        int col_local = fn + 16 * j + (lane & 15);
        size_t rg = (size_t)bm * 128 + row_local;
        int ng = bn * 128 + col_local;
        size_t addr = (size_t)(ng >> 9) * 33554432ull + rg * 512 + (ng & 511);
        xw[addr] = __float2bfloat16(acc[i][j][r]);
      }
}

// ---- k3: transpose U -> Ut [k4 (32)][dir*512+col (1024)][4] fp32 ----------
__global__ void prep_ut(const float* __restrict__ Ufw,
                        const float* __restrict__ Ubw,
                        float* __restrict__ Ut) {
  int idx = blockIdx.x * 512 + threadIdx.x;  // 0..131071
  int j = idx & 3;
  int dc = (idx >> 2) & 1023;
  int k4 = idx >> 12;
  int k = 4 * k4 + j;
  int c = dc & 511;
  const float* U = (dc >> 9) ? Ubw : Ufw;
  Ut[idx] = U[k * 512 + c];
}

// ---- k4: recurrence. One block per (dir,b). U column = 32 named f32x4
// loaded via asm volatile (non-remat, non-alloca -> forced VGPR residency).
__global__ __launch_bounds__(512)
__attribute__((amdgpu_waves_per_eu(2, 2)))  // 2 waves/EU -> 256-VGPR budget
void lstm_rec(
    const float* __restrict__ Ut, const float* __restrict__ b_fw,
    const float* __restrict__ b_bw, const __hip_bfloat16* __restrict__ xw,
    float* __restrict__ out) {
  __shared__ __attribute__((aligned(16))) float h_lds[128];
  __shared__ float g_lds[512];
  const int tid = threadIdx.x;           // 0..511 (gate column)
  const int dir = blockIdx.x >> 7;
  const int b = blockIdx.x & 127;
  const float bias = (dir ? b_bw : b_fw)[tid];

  // uj = U[4j..4j+3][col] via asm volatile: outputs are opaque, live-forever
  // values — the compiler cannot re-execute or rematerialize them.
  const float* up = Ut + ((size_t)dir * 512 + tid) * 4;
#define ULOAD(j)                                                   \
  f32x4 u##j;                                                      \
  {                                                                \
    const float* pj = up + (size_t)(j) * 4096;                     \
    asm volatile("global_load_dwordx4 %0, %1, off"                 \
                 : "=v"(u##j)                                      \
                 : "v"(pj));                                       \
  }
  ULOAD(0) ULOAD(1) ULOAD(2) ULOAD(3) ULOAD(4) ULOAD(5) ULOAD(6) ULOAD(7)
  ULOAD(8) ULOAD(9) ULOAD(10) ULOAD(11) ULOAD(12) ULOAD(13) ULOAD(14)
  ULOAD(15) ULOAD(16) ULOAD(17) ULOAD(18) ULOAD(19) ULOAD(20) ULOAD(21)
  ULOAD(22) ULOAD(23) ULOAD(24) ULOAD(25) ULOAD(26) ULOAD(27) ULOAD(28)
  ULOAD(29) ULOAD(30) ULOAD(31)
#undef ULOAD
  asm volatile("s_waitcnt vmcnt(0)" ::: "memory");
  __builtin_amdgcn_sched_barrier(0);  // rule #18: no hoisting past waitcnt

  if (tid < 128) h_lds[tid] = 0.f;
  float c = 0.f, h = 0.f, hfin = 0.f;
  __syncthreads();

  const __hip_bfloat16* xb =
      xw + (size_t)dir * 33554432ull + (size_t)b * 262144ull + tid;
  float* outb = out + (size_t)b * 131072 + dir * 128;

  int t = dir ? 511 : 0;
  const int st = dir ? -1 : 1;
  __hip_bfloat16 xc = xb[(size_t)t * 512];
  const float4* h4 = (const float4*)h_lds;
  const int grp = tid >> 7;  // 0:i 1:f 2:g 3:o (wave-uniform)

  for (int it = 0; it < 512; ++it) {
    const int tn = (it == 511) ? t : (t + st);
    __hip_bfloat16 xn = xb[(size_t)tn * 512];  // prefetch next step
    float a0 = 0.f, a1 = 0.f, a2 = 0.f, a3 = 0.f;
#define UFMA(j)                                        \
  {                                                    \
    float4 hv = h4[j]; /* LDS broadcast read */        \
    a0 = fmaf(hv.x, u##j.x, a0);                       \
    a1 = fmaf(hv.y, u##j.y, a1);                       \
    a2 = fmaf(hv.z, u##j.z, a2);                       \
    a3 = fmaf(hv.w, u##j.w, a3);                       \
  }
    UFMA(0) UFMA(1) UFMA(2) UFMA(3) UFMA(4) UFMA(5) UFMA(6) UFMA(7)
    UFMA(8) UFMA(9) UFMA(10) UFMA(11) UFMA(12) UFMA(13) UFMA(14) UFMA(15)
    UFMA(16) UFMA(17) UFMA(18) UFMA(19) UFMA(20) UFMA(21) UFMA(22) UFMA(23)
    UFMA(24) UFMA(25) UFMA(26) UFMA(27) UFMA(28) UFMA(29) UFMA(30) UFMA(31)
#undef UFMA
    float z = __bfloat162float(xc) + bias + ((a0 + a1) + (a2 + a3));
    float act = (grp == 2) ? fast_tanh(z) : fast_sigmoid(z);
    g_lds[tid] = act;
    __syncthreads();  // B1: gates visible
    if (tid < 128) {
      c = g_lds[128 + tid] * c + g_lds[tid] * g_lds[256 + tid];
      h = g_lds[384 + tid] * fast_tanh(c);
      hfin = h;
      h_lds[tid] = h;
    }
    __syncthreads();  // B2: h visible for next step
    if (tid < 128) outb[(size_t)t * 256 + tid] = h;  // overlaps next dot-prod
    xc = xn;
    t = tn;
  }
  if (tid < 128) {
    float* o2 = out + 16777216;  // after [B,T,2H]
    o2[dir * 32768 + b * 128 + tid] = hfin;           // h_fw / h_bw
    o2[dir * 32768 + 16384 + b * 128 + tid] = c;      // c_fw / c_bw
  }
}

// ---------------------------------------------------------------------------
extern "C" void kernel_launch(void* const* d_in, const int* in_sizes, int n_in,
                              void* d_out, int out_size, void* d_ws,
                              size_t ws_size, hipStream_t stream) {
  const int* tokens = (const int*)d_in[0];
  const float* emb = (const float*)d_in[1];
  const float* W_fw = (const float*)d_in[2];
  const float* U_fw = (const float*)d_in[3];
  const float* b_fw = (const float*)d_in[4];
  const float* W_bw = (const float*)d_in[5];
  const float* U_bw = (const float*)d_in[6];
  const float* b_bw = (const float*)d_in[7];
  float* out = (float*)d_out;

  char* ws = (char*)d_ws;
  __hip_bfloat16* embb = (__hip_bfloat16*)(ws);               // 16,384,000 B
  __hip_bfloat16* Wt = (__hip_bfloat16*)(ws + 16384000);      //    524,288 B
  __hip_bfloat16* xw = (__hip_bfloat16*)(ws + 16908288);      // 134,217,728 B
  float* Ut = (float*)(ws);  // 524,288 B — overlaps embb (dead after gemm_xw)

  prep_emb<<<8000, 256, 0, stream>>>((const float4*)emb, (ushort4*)embb,
                                     2048000);
  prep_wt<<<1024, 256, 0, stream>>>(W_fw, W_bw, Wt);
  gemm_xw<<<dim3(512, 8), 256, 0, stream>>>(tokens, embb, Wt, xw);
  prep_ut<<<256, 512, 0, stream>>>(U_fw, U_bw, Ut);  // after gemm: reuses embb
  lstm_rec<<<256, 512, 0, stream>>>(Ut, b_fw, b_bw, xw, out);
}